// Round 13
// baseline (38.475 us; speedup 1.0000x reference)
//
#include <hip/hip_runtime.h>

// Problem constants (fixed by setup_inputs: 64 graphs x 32 nodes)
constexpr int N_NODES = 2048;
constexpr int G       = 64;
constexpr int D       = 512;
constexpr int H       = 8;
constexpr int HD      = 64;
constexpr int E       = 16;
constexpr int M_EDGES = 16384;

typedef __attribute__((ext_vector_type(8))) _Float16 f16x8;
typedef __attribute__((ext_vector_type(4))) float f32x4;

__device__ __forceinline__ void load_lds16(const void* g, void* l) {
    __builtin_amdgcn_global_load_lds(
        (const __attribute__((address_space(1))) unsigned int*)g,
        (__attribute__((address_space(3))) unsigned int*)l, 16, 0, 0);
}

// ---------------------------------------------------------------------------
// QKV GEMM from raw fp32 inputs (prep eliminated).
//   C16[z] = fp16( nodes @ W_z + b_z ),  tile 64x64, BK=64, 4 waves.
// A: reg-staged fp32->fp16, ds_write_b128, swizzle slot^=(m&7).
// B: reg-staged fp32 [k][n] -> fp16 LDS [n][k] (in-block transpose),
//    k-pairs packed to ds_write_b32, swizzle slot^=((n>>1)&7).
// T14: issue loads(t+1) -> compute(t) -> cvt+write(t+1) -> barrier.
// ---------------------------------------------------------------------------
__global__ __launch_bounds__(256) void gemm_qkv_f32(
    const float* __restrict__ nodes,
    const float* __restrict__ Wq, const float* __restrict__ Wk,
    const float* __restrict__ Wv,
    const float* __restrict__ bq, const float* __restrict__ bk,
    const float* __restrict__ bv,
    _Float16* __restrict__ QKV16)
{
    const int z = blockIdx.z;
    const float* W    = (z == 0) ? Wq : (z == 1) ? Wk : Wv;
    const float* bias = (z == 0) ? bq : (z == 1) ? bk : bv;
    _Float16* C = QKV16 + (size_t)z * (size_t)N_NODES * D;

    const int row0 = blockIdx.y * 64;
    const int col0 = blockIdx.x * 64;

    __shared__ __align__(16) char As[2][8192];   // fp16 [m][k], swizzled
    __shared__ __align__(16) char Bs[2][8192];   // fp16 [n][k], swizzled

    const int t    = threadIdx.x;
    const int lane = t & 63;
    const int w    = t >> 6;
    const int wm   = w >> 1, wn = w & 1;

    // A-staging: task0 m = t>>3, task1 m+32; slot sla = t&7 (8 halfs)
    const int ma  = t >> 3;
    const int sla = t & 7;
    // B-staging: ng = t&15 (4 n each), kp = t>>4 and +16 (k-pairs)
    const int ng  = t & 15;
    const int kp0 = t >> 4;

    float4 ar[2][2], br[2][2];

    auto issueA = [&](int k0) {
        const float* p0 = nodes + (size_t)(row0 + ma) * D + k0 + sla * 8;
        const float* p1 = nodes + (size_t)(row0 + ma + 32) * D + k0 + sla * 8;
        ar[0][0] = *(const float4*)p0; ar[0][1] = *(const float4*)(p0 + 4);
        ar[1][0] = *(const float4*)p1; ar[1][1] = *(const float4*)(p1 + 4);
    };
    auto issueB = [&](int k0) {
        const float* q0 = W + (size_t)(k0 + 2 * kp0) * D + col0 + ng * 4;
        const float* q1 = W + (size_t)(k0 + 2 * (kp0 + 16)) * D + col0 + ng * 4;
        br[0][0] = *(const float4*)q0; br[0][1] = *(const float4*)(q0 + D);
        br[1][0] = *(const float4*)q1; br[1][1] = *(const float4*)(q1 + D);
    };
    auto writeAB = [&](int buf) {
#pragma unroll
        for (int task = 0; task < 2; ++task) {
            int m = ma + task * 32;
            float f[8] = { ar[task][0].x, ar[task][0].y, ar[task][0].z, ar[task][0].w,
                           ar[task][1].x, ar[task][1].y, ar[task][1].z, ar[task][1].w };
            union { _Float16 h[8]; int4 v; } pk;
#pragma unroll
            for (int e = 0; e < 8; ++e) pk.h[e] = (_Float16)f[e];
            *(int4*)(&As[buf][0] + m * 128 + ((sla ^ (m & 7)) << 4)) = pk.v;
        }
#pragma unroll
        for (int task = 0; task < 2; ++task) {
            int kk   = 2 * (kp0 + task * 16);
            int slot = kk >> 3;
            int off  = (kk & 7) * 2;
            float l4[4] = { br[task][0].x, br[task][0].y, br[task][0].z, br[task][0].w };
            float h4[4] = { br[task][1].x, br[task][1].y, br[task][1].z, br[task][1].w };
#pragma unroll
            for (int j = 0; j < 4; ++j) {
                int n = ng * 4 + j;
                union { _Float16 h[2]; unsigned u; } pk;
                pk.h[0] = (_Float16)l4[j];   // k = kk
                pk.h[1] = (_Float16)h4[j];   // k = kk+1
                *(unsigned*)(&Bs[buf][0] + n * 128 +
                             ((slot ^ ((n >> 1) & 7)) << 4) + off) = pk.u;
            }
        }
    };

    f32x4 acc[2][2] = {};

    issueA(0); issueB(0);
    writeAB(0);
    __syncthreads();

    int cur = 0;
    for (int step = 0; step < 8; ++step) {
        if (step < 7) { issueA((step + 1) * 64); issueB((step + 1) * 64); }

        f16x8 fa[2][2], fb[2][2];
#pragma unroll
        for (int mf = 0; mf < 2; ++mf) {
            int row = wm * 32 + mf * 16 + (lane & 15);
#pragma unroll
            for (int ks = 0; ks < 2; ++ks) {
                int ps = ((ks * 4 + (lane >> 4)) ^ (row & 7)) << 4;
                fa[mf][ks] = *(const f16x8*)(&As[cur][0] + row * 128 + ps);
            }
        }
#pragma unroll
        for (int nf = 0; nf < 2; ++nf) {
            int row = wn * 32 + nf * 16 + (lane & 15);
#pragma unroll
            for (int ks = 0; ks < 2; ++ks) {
                int ps = ((ks * 4 + (lane >> 4)) ^ ((row >> 1) & 7)) << 4;
                fb[nf][ks] = *(const f16x8*)(&Bs[cur][0] + row * 128 + ps);
            }
        }
#pragma unroll
        for (int mf = 0; mf < 2; ++mf)
#pragma unroll
            for (int nf = 0; nf < 2; ++nf)
#pragma unroll
                for (int ks = 0; ks < 2; ++ks)
                    acc[mf][nf] = __builtin_amdgcn_mfma_f32_16x16x32_f16(
                        fa[mf][ks], fb[nf][ks], acc[mf][nf], 0, 0, 0);

        if (step < 7) writeAB(cur ^ 1);
        __syncthreads();
        cur ^= 1;
    }

    // epilogue: C/D layout col=lane&15, row=(lane>>4)*4+reg
#pragma unroll
    for (int mf = 0; mf < 2; ++mf)
#pragma unroll
        for (int nf = 0; nf < 2; ++nf) {
            int col = col0 + wn * 32 + nf * 16 + (lane & 15);
            float bv = bias[col];
#pragma unroll
            for (int r = 0; r < 4; ++r) {
                int row = row0 + wm * 32 + mf * 16 + (lane >> 4) * 4 + r;
                C[(size_t)row * D + col] = (_Float16)(acc[mf][nf][r] + bv);
            }
        }
}

// ---------------------------------------------------------------------------
// OUT GEMM: A = AO16 fp16 (proven global_load_lds path, slot^=(m&7));
// B = Wo fp32 with in-block transpose staging (same scheme as qkv).
// ---------------------------------------------------------------------------
__global__ __launch_bounds__(256) void gemm_out_f32(
    const _Float16* __restrict__ AO16, const float* __restrict__ Wo,
    const float* __restrict__ bo, float* __restrict__ out)
{
    const int row0 = blockIdx.y * 64;
    const int col0 = blockIdx.x * 64;

    __shared__ __align__(16) char As[2][8192];
    __shared__ __align__(16) char Bs[2][8192];

    const int t    = threadIdx.x;
    const int lane = t & 63;
    const int w    = t >> 6;
    const int wm   = w >> 1, wn = w & 1;

    // A via global_load_lds: linear dest, inverse-swizzled source (proven)
    const int prow0 = t >> 3;
    const int lslot = (t & 7) ^ (prow0 & 7);
    // B reg-staging
    const int ng  = t & 15;
    const int kp0 = t >> 4;

    float4 br[2][2];

    auto stageA = [&](int buf, int k0) {
        size_t a0 = (size_t)(row0 + prow0) * 1024 + k0 * 2 + lslot * 16;
        size_t a1 = a0 + 32 * 1024;
        load_lds16((const char*)AO16 + a0, &As[buf][t * 16]);
        load_lds16((const char*)AO16 + a1, &As[buf][4096 + t * 16]);
    };
    auto issueB = [&](int k0) {
        const float* q0 = Wo + (size_t)(k0 + 2 * kp0) * D + col0 + ng * 4;
        const float* q1 = Wo + (size_t)(k0 + 2 * (kp0 + 16)) * D + col0 + ng * 4;
        br[0][0] = *(const float4*)q0; br[0][1] = *(const float4*)(q0 + D);
        br[1][0] = *(const float4*)q1; br[1][1] = *(const float4*)(q1 + D);
    };
    auto writeB = [&](int buf) {
#pragma unroll
        for (int task = 0; task < 2; ++task) {
            int kk   = 2 * (kp0 + task * 16);
            int slot = kk >> 3;
            int off  = (kk & 7) * 2;
            float l4[4] = { br[task][0].x, br[task][0].y, br[task][0].z, br[task][0].w };
            float h4[4] = { br[task][1].x, br[task][1].y, br[task][1].z, br[task][1].w };
#pragma unroll
            for (int j = 0; j < 4; ++j) {
                int n = ng * 4 + j;
                union { _Float16 h[2]; unsigned u; } pk;
                pk.h[0] = (_Float16)l4[j];
                pk.h[1] = (_Float16)h4[j];
                *(unsigned*)(&Bs[buf][0] + n * 128 +
                             ((slot ^ ((n >> 1) & 7)) << 4) + off) = pk.u;
            }
        }
    };

    f32x4 acc[2][2] = {};

    stageA(0, 0); issueB(0);
    writeB(0);
    __syncthreads();

    int cur = 0;
    for (int step = 0; step < 8; ++step) {
        if (step < 7) { stageA(cur ^ 1, (step + 1) * 64); issueB((step + 1) * 64); }

        f16x8 fa[2][2], fb[2][2];
#pragma unroll
        for (int mf = 0; mf < 2; ++mf) {
            int row = wm * 32 + mf * 16 + (lane & 15);
#pragma unroll
            for (int ks = 0; ks < 2; ++ks) {
                int ps = ((ks * 4 + (lane >> 4)) ^ (row & 7)) << 4;
                fa[mf][ks] = *(const f16x8*)(&As[cur][0] + row * 128 + ps);
            }
        }
#pragma unroll
        for (int nf = 0; nf < 2; ++nf) {
            int row = wn * 32 + nf * 16 + (lane & 15);
#pragma unroll
            for (int ks = 0; ks < 2; ++ks) {
                int ps = ((ks * 4 + (lane >> 4)) ^ ((row >> 1) & 7)) << 4;
                fb[nf][ks] = *(const f16x8*)(&Bs[cur][0] + row * 128 + ps);
            }
        }
#pragma unroll
        for (int mf = 0; mf < 2; ++mf)
#pragma unroll
            for (int nf = 0; nf < 2; ++nf)
#pragma unroll
                for (int ks = 0; ks < 2; ++ks)
                    acc[mf][nf] = __builtin_amdgcn_mfma_f32_16x16x32_f16(
                        fa[mf][ks], fb[nf][ks], acc[mf][nf], 0, 0, 0);

        if (step < 7) writeB(cur ^ 1);
        __syncthreads();
        cur ^= 1;
    }

#pragma unroll
    for (int mf = 0; mf < 2; ++mf)
#pragma unroll
        for (int nf = 0; nf < 2; ++nf) {
            int col = col0 + wn * 32 + nf * 16 + (lane & 15);
            float bv = bo[col];
#pragma unroll
            for (int r = 0; r < 4; ++r) {
                int row = row0 + wm * 32 + mf * 16 + (lane >> 4) * 4 + r;
                out[(size_t)row * D + col] = acc[mf][nf][r] + bv;
            }
        }
}

// ---------------------------------------------------------------------------
// Per-(graph, head) attention, 1024 thr (R10-proven body): inline LDS winner
// scan (16 iters), f16x8 vector staging, fp16 AO out.
// ---------------------------------------------------------------------------
__global__ __launch_bounds__(1024) void attn_kernel(
    const _Float16* __restrict__ QKV16,
    const float* __restrict__ edges, const float* __restrict__ We,
    const float* __restrict__ be,
    const int* __restrict__ snd, const int* __restrict__ rcv,
    _Float16* __restrict__ AO16)
{
    const int g = blockIdx.x;
    const int h = blockIdx.y;
    const int t = threadIdx.x;

    __shared__ float Qs[32][64];
    __shared__ float Ks[32][68];
    __shared__ float Vs[32][68];
    __shared__ float P[32][33];
    __shared__ int   win[1024];
    __shared__ float WesH[E];

    win[t & 1023] = -1;
    if (t < E) WesH[t] = We[t * H + h];

    // vector staging: threads 0..767 each move one f16x8 (z = t>>8)
    if (t < 768) {
        const int z   = t >> 8;
        const int v   = t & 255;
        const int row = v >> 3, c = v & 7;
        f16x8 x = *(const f16x8*)(QKV16 + (size_t)z * N_NODES * D +
                                  (size_t)(32 * g + row) * D + h * HD + c * 8);
        float* dst = (z == 0) ? &Qs[row][c * 8]
                   : (z == 1) ? &Ks[row][c * 8]
                              : &Vs[row][c * 8];
        float4 lo, hi;
        lo.x = (float)x[0]; lo.y = (float)x[1]; lo.z = (float)x[2]; lo.w = (float)x[3];
        hi.x = (float)x[4]; hi.y = (float)x[5]; hi.z = (float)x[6]; hi.w = (float)x[7];
        *(float4*)(dst)     = lo;
        *(float4*)(dst + 4) = hi;
    }
    __syncthreads();

    // winner scan: exact .set (last edge index wins), LDS-local
    for (int it = 0; it < M_EDGES / 1024; ++it) {
        int m = it * 1024 + t;
        int s = snd[m], r = rcv[m];
        if ((s >> 5) == g && (r >> 5) == g)
            atomicMax(&win[((r & 31) << 5) | (s & 31)], m);
    }
    __syncthreads();

    const int i = t >> 5;          // query row (receiver)
    const int j = t & 31;          // key col (sender)
    float s = 0.f;
#pragma unroll
    for (int d = 0; d < 64; ++d) s += Qs[i][d] * Ks[j][d];
    s *= 0.125f;

    int m = win[(i << 5) | j];
    if (m >= 0) {
        float v = be[h];
#pragma unroll
        for (int e = 0; e < E; ++e) v += edges[m * E + e] * WesH[e];
        s += v;
    }

    float mx = s;
#pragma unroll
    for (int o = 16; o > 0; o >>= 1) mx = fmaxf(mx, __shfl_xor(mx, o));
    float p = __expf(s - mx);
    float sum = p;
#pragma unroll
    for (int o = 16; o > 0; o >>= 1) sum += __shfl_xor(sum, o);
    p /= sum;
    P[i][j] = p;
    __syncthreads();

    float o0 = 0.f, o1 = 0.f;
#pragma unroll
    for (int kk = 0; kk < 32; ++kk) {
        float pv = P[i][kk];
        o0 += pv * Vs[kk][j];
        o1 += pv * Vs[kk][j + 32];
    }
    size_t oa = (size_t)(g * 32 + i) * D + h * HD;
    AO16[oa + j]      = (_Float16)o0;
    AO16[oa + j + 32] = (_Float16)o1;
}

// ---------------------------------------------------------------------------
extern "C" void kernel_launch(void* const* d_in, const int* in_sizes, int n_in,
                              void* d_out, int out_size, void* d_ws, size_t ws_size,
                              hipStream_t stream)
{
    const float* nodes = (const float*)d_in[0];
    const float* edges = (const float*)d_in[1];
    const float* Wq    = (const float*)d_in[2];
    const float* bq    = (const float*)d_in[3];
    const float* Wk    = (const float*)d_in[4];
    const float* bk    = (const float*)d_in[5];
    const float* Wv    = (const float*)d_in[6];
    const float* bv    = (const float*)d_in[7];
    const float* Wo    = (const float*)d_in[8];
    const float* bo    = (const float*)d_in[9];
    const float* We    = (const float*)d_in[10];
    const float* be    = (const float*)d_in[11];
    const int* senders   = (const int*)d_in[13];
    const int* receivers = (const int*)d_in[14];

    // workspace layout
    char* ws = (char*)d_ws;
    _Float16* QKV16 = (_Float16*)ws;                       // 6 MB (3x2048x512)
    _Float16* AO16  = QKV16 + (size_t)3 * N_NODES * D;     // 2 MB

    // 1) QKV GEMM from raw fp32 (prep folded in)
    gemm_qkv_f32<<<dim3(D / 64, N_NODES / 64, 3), 256, 0, stream>>>(
        nodes, Wq, Wk, Wv, bq, bk, bv, QKV16);

    // 2) attention (inline winner scan)
    attn_kernel<<<dim3(G, H), 1024, 0, stream>>>(
        QKV16, edges, We, be, senders, receivers, AO16);

    // 3) output GEMM from raw fp32 Wo
    gemm_out_f32<<<dim3(D / 64, N_NODES / 64), 256, 0, stream>>>(
        AO16, Wo, bo, (float*)d_out);
}

// Round 14
// 33.279 us; speedup vs baseline: 1.1561x; 1.1561x over previous
//
#include <hip/hip_runtime.h>

// Problem constants (fixed by setup_inputs: 64 graphs x 32 nodes)
constexpr int N_NODES = 2048;
constexpr int G       = 64;
constexpr int D       = 512;
constexpr int H       = 8;
constexpr int HD      = 64;
constexpr int E       = 16;
constexpr int M_EDGES = 16384;

typedef __attribute__((ext_vector_type(8))) _Float16 f16x8;
typedef __attribute__((ext_vector_type(4))) float f32x4;

__device__ __forceinline__ void load_lds16(const void* g, void* l) {
    __builtin_amdgcn_global_load_lds(
        (const __attribute__((address_space(1))) unsigned int*)g,
        (__attribute__((address_space(3))) unsigned int*)l, 16, 0, 0);
}

// ---------------------------------------------------------------------------
// PREP kernel: [0,512) node cast fp32->fp16; [512,1536) weight transpose+cast;
// [1536,1600) winner table init to -1.
// ---------------------------------------------------------------------------
__global__ __launch_bounds__(256) void prep_kernel(
    const float* __restrict__ nodes,
    const float* __restrict__ Wq, const float* __restrict__ Wk,
    const float* __restrict__ Wv, const float* __restrict__ Wo,
    _Float16* __restrict__ nA16, _Float16* __restrict__ wT16,
    int* __restrict__ winner)
{
    const int bid = blockIdx.x;
    const int t   = threadIdx.x;

    if (bid < 512) {
        int i = bid * 256 + t;                 // 8 floats each
        float4 v0 = ((const float4*)nodes)[2 * i];
        float4 v1 = ((const float4*)nodes)[2 * i + 1];
        float f[8] = { v0.x, v0.y, v0.z, v0.w, v1.x, v1.y, v1.z, v1.w };
        union { _Float16 h[8]; int4 v; } p;
#pragma unroll
        for (int e = 0; e < 8; ++e) p.h[e] = (_Float16)f[e];
        ((int4*)nA16)[i] = p.v;
        return;
    }

    if (bid < 1536) {
        int idx = bid - 512;                   // 0..1023
        int z   = idx >> 8;
        int rem = idx & 255;
        int k0  = (rem >> 4) * 32, n0 = (rem & 15) * 32;
        const float* W = (z == 0) ? Wq : (z == 1) ? Wk : (z == 2) ? Wv : Wo;
        __shared__ float tile[32][33];
        {
            int kr = t >> 3, nc4 = (t & 7) * 4;
            float4 v = *(const float4*)(W + (size_t)(k0 + kr) * D + n0 + nc4);
            tile[nc4 + 0][kr] = v.x;
            tile[nc4 + 1][kr] = v.y;
            tile[nc4 + 2][kr] = v.z;
            tile[nc4 + 3][kr] = v.w;
        }
        __syncthreads();
        {
            int nl = t >> 3, kq = (t & 7) * 4;
            union { _Float16 h[4]; uint2 v; } hi;
#pragma unroll
            for (int j = 0; j < 4; ++j)
                hi.h[j] = (_Float16)tile[nl][kq + j];
            size_t base = (size_t)z * D * D + (size_t)(n0 + nl) * D + k0 + kq;
            *(uint2*)(wT16 + base) = hi.v;
        }
        return;
    }

    // winner init: 64 blocks x 256 thr x int4 = 64K ints = G*1024
    ((int4*)winner)[(bid - 1536) * 256 + t] = make_int4(-1, -1, -1, -1);
}

// ---------------------------------------------------------------------------
// fp16 MFMA GEMM (R10-proven dbuf structure): C = A@B' + bias.
// ---------------------------------------------------------------------------
template <typename CT>
__device__ __forceinline__ void gemm_body(
    const _Float16* __restrict__ A, const _Float16* __restrict__ B,
    const float* __restrict__ bias, CT* __restrict__ C,
    int row0, int col0)
{
    __shared__ __align__(16) char lds[2][2][8192];   // [buf][A,B]

    const int t    = threadIdx.x;
    const int lane = t & 63;
    const int w    = t >> 6;
    const int wm   = w >> 1, wn = w & 1;

    const int prow0 = t >> 3;
    const int lslot = (t & 7) ^ (prow0 & 7);

    auto stage = [&](int buf, int k0) {
        size_t a0 = (size_t)(row0 + prow0) * 1024 + k0 * 2 + lslot * 16;
        size_t a1 = a0 + 32 * 1024;
        size_t b0 = (size_t)(col0 + prow0) * 1024 + k0 * 2 + lslot * 16;
        size_t b1 = b0 + 32 * 1024;
        load_lds16((const char*)A + a0, &lds[buf][0][t * 16]);
        load_lds16((const char*)A + a1, &lds[buf][0][4096 + t * 16]);
        load_lds16((const char*)B + b0, &lds[buf][1][t * 16]);
        load_lds16((const char*)B + b1, &lds[buf][1][4096 + t * 16]);
    };

    f32x4 acc[2][2] = {};

    stage(0, 0);
    __syncthreads();

    int cur = 0;
    for (int step = 0; step < 8; ++step) {
        if (step < 7) stage(cur ^ 1, (step + 1) * 64);

        f16x8 fa[2][2], fb[2][2];
#pragma unroll
        for (int mf = 0; mf < 2; ++mf) {
            int row = wm * 32 + mf * 16 + (lane & 15);
#pragma unroll
            for (int ks = 0; ks < 2; ++ks) {
                int ps = ((ks * 4 + (lane >> 4)) ^ (row & 7)) << 4;
                fa[mf][ks] = *(const f16x8*)&lds[cur][0][row * 128 + ps];
            }
        }
#pragma unroll
        for (int nf = 0; nf < 2; ++nf) {
            int row = wn * 32 + nf * 16 + (lane & 15);
#pragma unroll
            for (int ks = 0; ks < 2; ++ks) {
                int ps = ((ks * 4 + (lane >> 4)) ^ (row & 7)) << 4;
                fb[nf][ks] = *(const f16x8*)&lds[cur][1][row * 128 + ps];
            }
        }
#pragma unroll
        for (int mf = 0; mf < 2; ++mf)
#pragma unroll
            for (int nf = 0; nf < 2; ++nf)
#pragma unroll
                for (int ks = 0; ks < 2; ++ks)
                    acc[mf][nf] = __builtin_amdgcn_mfma_f32_16x16x32_f16(
                        fa[mf][ks], fb[nf][ks], acc[mf][nf], 0, 0, 0);

        __syncthreads();
        cur ^= 1;
    }

#pragma unroll
    for (int mf = 0; mf < 2; ++mf)
#pragma unroll
        for (int nf = 0; nf < 2; ++nf) {
            int col = col0 + wn * 32 + nf * 16 + (lane & 15);
            float bv = bias[col];
#pragma unroll
            for (int r = 0; r < 4; ++r) {
                int row = row0 + wm * 32 + mf * 16 + (lane >> 4) * 4 + r;
                C[(size_t)row * D + col] = (CT)(acc[mf][nf][r] + bv);
            }
        }
}

struct GemmArgs {
    const _Float16 *A, *BT;
    const float* bias[3];
    void* C;
};

// qkv GEMM + piggybacked edge-winner scan (z==3 slice, 64 active blocks on
// CUs that are idle during the 768-block GEMM; winner init'd by prep).
__global__ __launch_bounds__(256) void gemm_qkv_kernel(
    GemmArgs a, const int* __restrict__ snd, const int* __restrict__ rcv,
    int* __restrict__ winner)
{
    const int z = blockIdx.z;
    if (z == 3) {
        if (blockIdx.y < 8) {
            int m = (blockIdx.y * 8 + blockIdx.x) * 256 + threadIdx.x;
            int s = snd[m], r = rcv[m];
            if ((s >> 5) == (r >> 5))
                atomicMax(&winner[((r >> 5) << 10) | ((r & 31) << 5) | (s & 31)], m);
        }
        return;
    }
    gemm_body<_Float16>(a.A, a.BT + (size_t)z * D * D, a.bias[z],
                        (_Float16*)a.C + (size_t)z * (size_t)N_NODES * D,
                        blockIdx.y * 64, blockIdx.x * 64);
}

__global__ __launch_bounds__(256) void gemm_out_kernel(GemmArgs a)
{
    gemm_body<float>(a.A, a.BT, a.bias[0], (float*)a.C,
                     blockIdx.y * 64, blockIdx.x * 64);
}

// ---------------------------------------------------------------------------
// Per-(graph, head) attention, 256 threads (R11 phase-A proven lane math),
// vectorized f16x8 staging, precomputed winner table. fp16 AO out.
// ---------------------------------------------------------------------------
__global__ __launch_bounds__(256) void attn_kernel(
    const _Float16* __restrict__ QKV16,
    const float* __restrict__ edges, const float* __restrict__ We,
    const float* __restrict__ be, const int* __restrict__ winner,
    _Float16* __restrict__ AO16)
{
    const int g = blockIdx.x;
    const int h = blockIdx.y;
    const int t = threadIdx.x;

    __shared__ float Qs[32][64];
    __shared__ float Ks[32][68];
    __shared__ float Vs[32][68];
    __shared__ float P[32][33];
    __shared__ float WesH[E];

    if (t < E) WesH[t] = We[t * H + h];

    // stage Q/K/V fp16 -> fp32 LDS: one f16x8 per thread per array
    {
        const int row = t >> 3, c = t & 7;
        const size_t ga = (size_t)(32 * g + row) * D + h * HD + c * 8;
#pragma unroll
        for (int z = 0; z < 3; ++z) {
            f16x8 v = *(const f16x8*)(QKV16 + (size_t)z * N_NODES * D + ga);
            float* dst = (z == 0) ? &Qs[row][c * 8]
                       : (z == 1) ? &Ks[row][c * 8]
                                  : &Vs[row][c * 8];
            float4 lo, hi;
            lo.x = (float)v[0]; lo.y = (float)v[1];
            lo.z = (float)v[2]; lo.w = (float)v[3];
            hi.x = (float)v[4]; hi.y = (float)v[5];
            hi.z = (float)v[6]; hi.w = (float)v[7];
            *(float4*)(dst)     = lo;
            *(float4*)(dst + 4) = hi;
        }
    }
    __syncthreads();

    // scores + edge bias + softmax: thread = (i = t>>3, j4 = (t&7)*4)
    const int i  = t >> 3;
    const int j4 = (t & 7) * 4;
    {
        float s[4] = {};
        for (int d = 0; d < HD; ++d) {
            float qv = Qs[i][d];
#pragma unroll
            for (int r = 0; r < 4; ++r)
                s[r] += qv * Ks[j4 + r][d];
        }
        const int* winG = winner + (g << 10);
        float besH = be[h];
#pragma unroll
        for (int r = 0; r < 4; ++r) {
            s[r] *= 0.125f;
            int m = winG[(i << 5) | (j4 + r)];
            if (m >= 0) {
                float v = besH;
#pragma unroll
                for (int e = 0; e < E; ++e) v += edges[m * E + e] * WesH[e];
                s[r] += v;
            }
        }
        float mx = fmaxf(fmaxf(s[0], s[1]), fmaxf(s[2], s[3]));
#pragma unroll
        for (int o = 4; o > 0; o >>= 1) mx = fmaxf(mx, __shfl_xor(mx, o));
        float p[4], sum = 0.f;
#pragma unroll
        for (int r = 0; r < 4; ++r) { p[r] = __expf(s[r] - mx); sum += p[r]; }
#pragma unroll
        for (int o = 4; o > 0; o >>= 1) sum += __shfl_xor(sum, o);
        float inv = 1.0f / sum;
#pragma unroll
        for (int r = 0; r < 4; ++r) P[i][j4 + r] = p[r] * inv;
    }
    __syncthreads();

    // PV: thread (i, dq = (t&7)*8) -> 8 outputs; 16B AO16 store
    {
        const int dq = (t & 7) * 8;
        float o[8] = {};
        for (int kk = 0; kk < 32; ++kk) {
            float pv = P[i][kk];
            float4 v0 = *(const float4*)&Vs[kk][dq];
            float4 v1 = *(const float4*)&Vs[kk][dq + 4];
            o[0] += pv * v0.x; o[1] += pv * v0.y;
            o[2] += pv * v0.z; o[3] += pv * v0.w;
            o[4] += pv * v1.x; o[5] += pv * v1.y;
            o[6] += pv * v1.z; o[7] += pv * v1.w;
        }
        union { _Float16 h8[8]; int4 v; } pk;
#pragma unroll
        for (int dd = 0; dd < 8; ++dd) pk.h8[dd] = (_Float16)o[dd];
        *(int4*)(AO16 + (size_t)(32 * g + i) * D + h * HD + dq) = pk.v;
    }
}

// ---------------------------------------------------------------------------
extern "C" void kernel_launch(void* const* d_in, const int* in_sizes, int n_in,
                              void* d_out, int out_size, void* d_ws, size_t ws_size,
                              hipStream_t stream)
{
    const float* nodes = (const float*)d_in[0];
    const float* edges = (const float*)d_in[1];
    const float* Wq    = (const float*)d_in[2];
    const float* bq    = (const float*)d_in[3];
    const float* Wk    = (const float*)d_in[4];
    const float* bk    = (const float*)d_in[5];
    const float* Wv    = (const float*)d_in[6];
    const float* bv    = (const float*)d_in[7];
    const float* Wo    = (const float*)d_in[8];
    const float* bo    = (const float*)d_in[9];
    const float* We    = (const float*)d_in[10];
    const float* be    = (const float*)d_in[11];
    const int* senders   = (const int*)d_in[13];
    const int* receivers = (const int*)d_in[14];

    // workspace layout
    char* ws = (char*)d_ws;
    _Float16* nA16   = (_Float16*)ws;                      // 2 MB
    _Float16* wT16   = nA16 + (size_t)N_NODES * D;         // 2 MB (4x512x512)
    _Float16* QKV16  = wT16 + (size_t)4 * D * D;           // 6 MB (3x2048x512)
    _Float16* AO16   = QKV16 + (size_t)3 * N_NODES * D;    // 2 MB
    int*      winner = (int*)(AO16 + (size_t)N_NODES * D); // 256 KB

    // 1) prep: node cast + weight transpose + winner init
    prep_kernel<<<1600, 256, 0, stream>>>(nodes, Wq, Wk, Wv, Wo,
                                          nA16, wT16, winner);

    // 2) QKV GEMM -> fp16, + edge-winner scan on the z=3 slice
    GemmArgs qkv;
    qkv.A = nA16;
    qkv.BT = wT16;
    qkv.bias[0] = bq; qkv.bias[1] = bk; qkv.bias[2] = bv;
    qkv.C = QKV16;
    gemm_qkv_kernel<<<dim3(D / 64, N_NODES / 64, 4), 256, 0, stream>>>(
        qkv, senders, receivers, winner);

    // 3) attention (reads precomputed winner)
    attn_kernel<<<dim3(G, H), 256, 0, stream>>>(
        QKV16, edges, We, be, winner, AO16);

    // 4) output GEMM (Wo at slot 3)
    GemmArgs og;
    og.A = AO16;
    og.BT = wT16 + (size_t)3 * D * D;
    og.bias[0] = bo; og.bias[1] = bo; og.bias[2] = bo;
    og.C = d_out;
    gemm_out_kernel<<<dim3(D / 64, N_NODES / 64), 256, 0, stream>>>(og);
}